// Round 7
// baseline (369.808 us; speedup 1.0000x reference)
//
#include <hip/hip_runtime.h>

// Generalized Lotka-Volterra, RK4, D=64, batch 2048, 255 steps,
// trajectory out (batch, 256, 64) fp32 — MFMA formulation.
//
// Per wave: 16 batch elements. State X (16 batch x 64 comp) lives in MFMA
// C-layout fragments: x[t][q] = X[b=4g+q][d=p+16t], g=lane>>4, p=lane&15.
// feval: Y = X @ E^T via 8x mfma_f32_16x16x32_f16 (4 d-tiles x 2 K-halves),
// then f = X .* (r - X + Y) elementwise exact fp32 (E = A + I; diagonal and
// r never touch f16 — only the small E-coupling term is f16).
//
// Feedback transpose C-layout -> A-fragment via wave-private LDS, transposed
// store xT[d][b] with row stride 17 dwords (bank-conflict <= 2-way, free):
//   write: lds[(p+16t)*17 + 4g+q]  (16x ds_write_b32)
//   read : lds[(32h+8g+j)*17 + p]  (16x ds_read_b32) -> cvt_pkrtz -> A-frag
// Wave-synchronous: lgkmcnt(0) between write and read (DS in-order per wave).
//
// Fragment layouts (gfx950 16x16x32): A[row=p][k=8g+j], B[k=8g+j][col=p],
// C[row=4g+q][col=p] (C verified per guide m89/m91).
//
// Parallelism: 2048/16 = 128 one-wave blocks (structural; MFMA M=16 minimum).

constexpr int D  = 64;    // state dimension
constexpr int NT = 256;   // trajectory length (255 RK4 steps)
constexpr int BW = 16;    // batch elements per wave (MFMA M)

typedef _Float16 f16x8 __attribute__((ext_vector_type(8)));
typedef float    f32x4 __attribute__((ext_vector_type(4)));

__device__ __forceinline__ uint32_t pkrtz(float lo, float hi) {
    return __builtin_bit_cast(uint32_t, __builtin_amdgcn_cvt_pkrtz(lo, hi));
}

// f(X) = X .* (r - X + X@E^T): input/output in C-layout reg arrays [4][4].
#define FEVAL(XT, F)                                                          \
    do {                                                                      \
        _Pragma("unroll")                                                     \
        for (int t = 0; t < 4; ++t)                                           \
            _Pragma("unroll")                                                 \
            for (int q = 0; q < 4; ++q)                                       \
                xT[wbase + 272 * t + q] = XT[t][q];                           \
        asm volatile("s_waitcnt lgkmcnt(0)" ::: "memory");                    \
        float xr[2][8];                                                       \
        _Pragma("unroll")                                                     \
        for (int h = 0; h < 2; ++h)                                           \
            _Pragma("unroll")                                                 \
            for (int j = 0; j < 8; ++j)                                       \
                xr[h][j] = xT[rbase + 544 * h + 17 * j];                      \
        f16x8 af[2];                                                          \
        _Pragma("unroll")                                                     \
        for (int h = 0; h < 2; ++h) {                                         \
            union { uint32_t u[4]; f16x8 v; } un_;                            \
            un_.u[0] = pkrtz(xr[h][0], xr[h][1]);                             \
            un_.u[1] = pkrtz(xr[h][2], xr[h][3]);                             \
            un_.u[2] = pkrtz(xr[h][4], xr[h][5]);                             \
            un_.u[3] = pkrtz(xr[h][6], xr[h][7]);                             \
            af[h] = un_.v;                                                    \
        }                                                                     \
        _Pragma("unroll")                                                     \
        for (int t = 0; t < 4; ++t) {                                         \
            f32x4 acc = {0.f, 0.f, 0.f, 0.f};                                 \
            acc = __builtin_amdgcn_mfma_f32_16x16x32_f16(af[0], bf[t][0], acc, 0, 0, 0); \
            acc = __builtin_amdgcn_mfma_f32_16x16x32_f16(af[1], bf[t][1], acc, 0, 0, 0); \
            _Pragma("unroll")                                                 \
            for (int q = 0; q < 4; ++q)                                       \
                F[t][q] = XT[t][q] * ((r4[t] - XT[t][q]) + acc[q]);           \
        }                                                                     \
    } while (0)

__global__ __launch_bounds__(64, 1)
void glv_rk4_mfma(const float* __restrict__ x0,
                  const float* __restrict__ r,
                  const float* __restrict__ A,
                  const float* __restrict__ tgrid,
                  float* __restrict__ out)
{
    const int lane = threadIdx.x & 63;
    const int g    = lane >> 4;
    const int p    = lane & 15;
    const int b0   = blockIdx.x * BW;          // first batch elem of this wave

    __shared__ float xT[D * 17];               // transposed state, pad-17 rows

    // LDS address bases (dword indices into xT)
    const int wbase = 17 * p + 4 * g;          // + (272*t + q)
    const int rbase = 136 * g + p;             // + (544*h + 17*j)

    // Stationary B fragments: bf[t][h] elem j = E[16t+p][32h+8g+j], E = A+I.
    f16x8 bf[4][2];
#pragma unroll
    for (int t = 0; t < 4; ++t) {
#pragma unroll
        for (int h = 0; h < 2; ++h) {
            const int row  = 16 * t + p;
            const int col0 = 32 * h + 8 * g;
            const float4 v0 = *reinterpret_cast<const float4*>(A + row * D + col0);
            const float4 v1 = *reinterpret_cast<const float4*>(A + row * D + col0 + 4);
            float e[8] = {v0.x, v0.y, v0.z, v0.w, v1.x, v1.y, v1.z, v1.w};
#pragma unroll
            for (int j = 0; j < 8; ++j)
                if (row == col0 + j) e[j] += 1.0f;
            union { uint32_t u[4]; f16x8 v; } un;
            un.u[0] = pkrtz(e[0], e[1]);
            un.u[1] = pkrtz(e[2], e[3]);
            un.u[2] = pkrtz(e[4], e[5]);
            un.u[3] = pkrtz(e[6], e[7]);
            bf[t][h] = un.v;
        }
    }
    // Anti-sink fence: keep B fragments resident across the time loop.
#pragma unroll
    for (int t = 0; t < 4; ++t)
#pragma unroll
        for (int h = 0; h < 2; ++h)
            asm volatile("" : "+v"(bf[t][h]));

    // r in C-layout; RK4 constants.
    float r4[4];
#pragma unroll
    for (int t = 0; t < 4; ++t) r4[t] = r[p + 16 * t];

    const float dt = tgrid[1] - tgrid[0];
    const float h2 = 0.5f * dt;
    const float h6 = dt * (1.0f / 6.0f);

    // State + output pointers (one row base per q).
    float x[4][4];
    float* op[4];
#pragma unroll
    for (int q = 0; q < 4; ++q) {
        const int b = b0 + 4 * g + q;
        op[q] = out + (size_t)b * NT * D + p;
#pragma unroll
        for (int t = 0; t < 4; ++t)
            x[t][q] = x0[b * D + p + 16 * t];
    }

    // t = 0 output is x0.
#pragma unroll
    for (int q = 0; q < 4; ++q)
#pragma unroll
        for (int t = 0; t < 4; ++t)
            op[q][16 * t] = x[t][q];

    float s[4][4], xt[4][4], k[4][4];

    for (int ts = 1; ts < NT; ++ts) {
        FEVAL(x, k);                                   // k1
#pragma unroll
        for (int t = 0; t < 4; ++t)
#pragma unroll
            for (int q = 0; q < 4; ++q) {
                s[t][q]  = fmaf(h6, k[t][q], x[t][q]);
                xt[t][q] = fmaf(h2, k[t][q], x[t][q]);
            }
        FEVAL(xt, k);                                  // k2
#pragma unroll
        for (int t = 0; t < 4; ++t)
#pragma unroll
            for (int q = 0; q < 4; ++q) {
                s[t][q]  = fmaf(2.0f * h6, k[t][q], s[t][q]);
                xt[t][q] = fmaf(h2, k[t][q], x[t][q]);
            }
        FEVAL(xt, k);                                  // k3
#pragma unroll
        for (int t = 0; t < 4; ++t)
#pragma unroll
            for (int q = 0; q < 4; ++q) {
                s[t][q]  = fmaf(2.0f * h6, k[t][q], s[t][q]);
                xt[t][q] = fmaf(dt, k[t][q], x[t][q]);
            }
        FEVAL(xt, k);                                  // k4
#pragma unroll
        for (int t = 0; t < 4; ++t)
#pragma unroll
            for (int q = 0; q < 4; ++q)
                x[t][q] = fmaf(h6, k[t][q], s[t][q]);

        // Store step ts: 16 dword stores, 64B-coalesced per 16-lane group.
#pragma unroll
        for (int q = 0; q < 4; ++q) {
            float* o = op[q] + ts * D;
#pragma unroll
            for (int t = 0; t < 4; ++t)
                o[16 * t] = x[t][q];
        }
    }
}

extern "C" void kernel_launch(void* const* d_in, const int* in_sizes, int n_in,
                              void* d_out, int out_size, void* d_ws, size_t ws_size,
                              hipStream_t stream) {
    const float* x0    = (const float*)d_in[0];
    const float* r     = (const float*)d_in[1];
    const float* A     = (const float*)d_in[2];
    const float* tgrid = (const float*)d_in[3];
    float* out         = (float*)d_out;

    const int batch = in_sizes[0] / D;          // 2048
    dim3 grid(batch / BW);                      // 128 one-wave blocks
    dim3 block(64);

    glv_rk4_mfma<<<grid, block, 0, stream>>>(x0, r, A, tgrid, out);
}

// Round 8
// 262.261 us; speedup vs baseline: 1.4101x; 1.4101x over previous
//
#include <hip/hip_runtime.h>

// Generalized Lotka-Volterra, RK4, D=64, batch 2048, 255 steps,
// trajectory out (batch, 256, 64) fp32 — MFMA with ZERO-SHUFFLE FEEDBACK.
//
// Per wave: 16 batch elements (p = lane&15 indexes batch). State kept in the
// "need layout": lane (g,p) holds x[t][q] = X[batch p][d(t,g,q)],
//   d(t,g,q) = 32*(t>>1) + 8*g + 4*(t&1) + q.
// feval computes Ytilde = E_perm @ X^T where E_perm's rows are permuted so
// that MFMA tile t's C-layout output lands each Y value in EXACTLY the lane
// and register the next B-fragment needs:
//   position rho = 16t+4g+q  holds original row  d = 32(t>>1)+8g+4(t&1)+q.
// Hence feedback = 8x v_cvt_pkrtz (pack x[t][q] pairs into f16x8 B-frags).
// No LDS, no waitcnt, no cross-lane ops anywhere in the RK4 loop.
//
// Fragment layouts (verified on-HW by round 7's passing kernel):
//   A[row=p][k=8g+j], B[k=8g+j][col=p], C[row=4g+q][col=p].
// A-operand: stationary af[t][kh] elem j = E[rE][32kh+8g+j],
//   rE = 32(t>>1) + 8*(p>>2) + 4*(t&1) + (p&3)   (E = A + I, f16).
// Diagonal (-x) and growth r stay exact fp32: f = x .* ((r - x) + E@x);
// (r - x) is folded into the MFMA C-initializer for free.
//
// Trajectory store: lane holds batch p's components -> scattered vs memory
// layout, so re-coalesce via a once-per-step LDS transpose (pad-17 rows,
// <=2-way banks = free; 32 DS ops/step, OFF the feval critical path).

constexpr int D  = 64;    // state dimension
constexpr int NT = 256;   // trajectory length (255 RK4 steps)
constexpr int BW = 16;    // batch elements per wave (MFMA N)

typedef _Float16 f16x8 __attribute__((ext_vector_type(8)));
typedef float    f32x4 __attribute__((ext_vector_type(4)));

__device__ __forceinline__ uint32_t pkrtz(float lo, float hi) {
    return __builtin_bit_cast(uint32_t, __builtin_amdgcn_cvt_pkrtz(lo, hi));
}

// f(XT) = XT .* ((r - XT) + E@XT); XT, F are float[4][4] in the need-layout.
#define FEVAL(XT, F)                                                          \
    do {                                                                      \
        union { uint32_t u[4]; f16x8 v; } u0_, u1_;                           \
        u0_.u[0] = pkrtz(XT[0][0], XT[0][1]);                                 \
        u0_.u[1] = pkrtz(XT[0][2], XT[0][3]);                                 \
        u0_.u[2] = pkrtz(XT[1][0], XT[1][1]);                                 \
        u0_.u[3] = pkrtz(XT[1][2], XT[1][3]);                                 \
        u1_.u[0] = pkrtz(XT[2][0], XT[2][1]);                                 \
        u1_.u[1] = pkrtz(XT[2][2], XT[2][3]);                                 \
        u1_.u[2] = pkrtz(XT[3][0], XT[3][1]);                                 \
        u1_.u[3] = pkrtz(XT[3][2], XT[3][3]);                                 \
        const f16x8 bf0 = u0_.v, bf1 = u1_.v;                                 \
        _Pragma("unroll")                                                     \
        for (int t_ = 0; t_ < 4; ++t_) {                                      \
            f32x4 c_;                                                         \
            _Pragma("unroll")                                                 \
            for (int q_ = 0; q_ < 4; ++q_) c_[q_] = rl[t_][q_] - XT[t_][q_];  \
            c_ = __builtin_amdgcn_mfma_f32_16x16x32_f16(af[t_][0], bf0, c_, 0, 0, 0); \
            c_ = __builtin_amdgcn_mfma_f32_16x16x32_f16(af[t_][1], bf1, c_, 0, 0, 0); \
            _Pragma("unroll")                                                 \
            for (int q_ = 0; q_ < 4; ++q_) F[t_][q_] = XT[t_][q_] * c_[q_];   \
        }                                                                     \
    } while (0)

// Coalesce step TS through LDS: write x in (d, batch) form, read d-contiguous.
#define STORE_STEP(TS)                                                        \
    do {                                                                      \
        _Pragma("unroll")                                                     \
        for (int t_ = 0; t_ < 4; ++t_)                                        \
            _Pragma("unroll")                                                 \
            for (int q_ = 0; q_ < 4; ++q_)                                    \
                xT[(dbase[t_] + q_) * 17 + p] = x[t_][q_];                    \
        asm volatile("s_waitcnt lgkmcnt(0)" ::: "memory");                    \
        _Pragma("unroll")                                                     \
        for (int i_ = 0; i_ < 16; ++i_)                                       \
            outp[(size_t)i_ * NT * D + (size_t)(TS) * D + lane] =             \
                xT[lane * 17 + i_];                                           \
    } while (0)

__global__ __launch_bounds__(64, 1)
void glv_rk4_mfma(const float* __restrict__ x0,
                  const float* __restrict__ r,
                  const float* __restrict__ A,
                  const float* __restrict__ tgrid,
                  float* __restrict__ out)
{
    const int lane = threadIdx.x & 63;
    const int g    = lane >> 4;
    const int p    = lane & 15;
    const int b0   = blockIdx.x * BW;          // first batch elem of this wave

    __shared__ float xT[D * 17];               // store-staging only

    int dbase[4];
#pragma unroll
    for (int t = 0; t < 4; ++t) dbase[t] = 32 * (t >> 1) + 8 * g + 4 * (t & 1);

    // Stationary A-fragments of permuted E (E = A + I).
    f16x8 af[4][2];
#pragma unroll
    for (int t = 0; t < 4; ++t) {
        const int rE = 32 * (t >> 1) + 8 * (p >> 2) + 4 * (t & 1) + (p & 3);
#pragma unroll
        for (int kh = 0; kh < 2; ++kh) {
            const int c0 = 32 * kh + 8 * g;
            const float4 v0 = *reinterpret_cast<const float4*>(A + rE * D + c0);
            const float4 v1 = *reinterpret_cast<const float4*>(A + rE * D + c0 + 4);
            float e[8] = {v0.x, v0.y, v0.z, v0.w, v1.x, v1.y, v1.z, v1.w};
#pragma unroll
            for (int j = 0; j < 8; ++j)
                if (rE == c0 + j) e[j] += 1.0f;
            union { uint32_t u[4]; f16x8 v; } un;
            un.u[0] = pkrtz(e[0], e[1]);
            un.u[1] = pkrtz(e[2], e[3]);
            un.u[2] = pkrtz(e[4], e[5]);
            un.u[3] = pkrtz(e[6], e[7]);
            af[t][kh] = un.v;
        }
    }
    // Anti-sink fence: keep the E fragments register-resident across the loop.
#pragma unroll
    for (int t = 0; t < 4; ++t)
#pragma unroll
        for (int kh = 0; kh < 2; ++kh)
            asm volatile("" : "+v"(af[t][kh]));

    // r and x0 in the need-layout (float4: dbase is a multiple of 4).
    float rl[4][4], x[4][4];
#pragma unroll
    for (int t = 0; t < 4; ++t) {
        const float4 rv = *reinterpret_cast<const float4*>(r + dbase[t]);
        rl[t][0] = rv.x; rl[t][1] = rv.y; rl[t][2] = rv.z; rl[t][3] = rv.w;
        const float4 xv =
            *reinterpret_cast<const float4*>(x0 + (b0 + p) * D + dbase[t]);
        x[t][0] = xv.x; x[t][1] = xv.y; x[t][2] = xv.z; x[t][3] = xv.w;
    }

    const float dt = tgrid[1] - tgrid[0];
    const float h2 = 0.5f * dt;
    const float h6 = dt * (1.0f / 6.0f);
    float* const outp = out + (size_t)b0 * NT * D;

    STORE_STEP(0);                             // t = 0 output is x0

    float s[4][4], xt[4][4], k[4][4];

    for (int ts = 1; ts < NT; ++ts) {
        FEVAL(x, k);                                   // k1
#pragma unroll
        for (int t = 0; t < 4; ++t)
#pragma unroll
            for (int q = 0; q < 4; ++q) {
                s[t][q]  = fmaf(h6, k[t][q], x[t][q]);
                xt[t][q] = fmaf(h2, k[t][q], x[t][q]);
            }
        FEVAL(xt, k);                                  // k2
#pragma unroll
        for (int t = 0; t < 4; ++t)
#pragma unroll
            for (int q = 0; q < 4; ++q) {
                s[t][q]  = fmaf(2.0f * h6, k[t][q], s[t][q]);
                xt[t][q] = fmaf(h2, k[t][q], x[t][q]);
            }
        FEVAL(xt, k);                                  // k3
#pragma unroll
        for (int t = 0; t < 4; ++t)
#pragma unroll
            for (int q = 0; q < 4; ++q) {
                s[t][q]  = fmaf(2.0f * h6, k[t][q], s[t][q]);
                xt[t][q] = fmaf(dt, k[t][q], x[t][q]);
            }
        FEVAL(xt, k);                                  // k4
#pragma unroll
        for (int t = 0; t < 4; ++t)
#pragma unroll
            for (int q = 0; q < 4; ++q)
                x[t][q] = fmaf(h6, k[t][q], s[t][q]);

        STORE_STEP(ts);
    }
}

extern "C" void kernel_launch(void* const* d_in, const int* in_sizes, int n_in,
                              void* d_out, int out_size, void* d_ws, size_t ws_size,
                              hipStream_t stream) {
    const float* x0    = (const float*)d_in[0];
    const float* r     = (const float*)d_in[1];
    const float* A     = (const float*)d_in[2];
    const float* tgrid = (const float*)d_in[3];
    float* out         = (float*)d_out;

    const int batch = in_sizes[0] / D;          // 2048
    dim3 grid(batch / BW);                      // 128 one-wave blocks
    dim3 block(64);

    glv_rk4_mfma<<<grid, block, 0, stream>>>(x0, r, A, tgrid, out);
}